// Round 1
// baseline (1009.115 us; speedup 1.0000x reference)
//
#include <hip/hip_runtime.h>

// Problem constants
#define DD   768          // feature dim
#define BB   256          // batch
#define NN   196          // tokens per modality
#define KK1  112          // intra top-k
#define KK2  224          // inter top-k
#define RTOT (BB*3)       // 768 rows (b,modality/query)
#define CAND (2*NN)       // 392 inter candidates per query

// -------- workspace layout (bytes) --------
// Qh     double[768*768]        @ 0          (4,718,592)
// Td     double[768*768]        @ 4718592    (4,718,592)
// Lintra double[768*196]        @ 9437184    (1,204,224)
// Linter double[768*392]        @ 10641408   (2,408,448)
// mask   uint8 [3*256*196]      @ 13049856   (150,528)
// total ~13.2 MB

// ---------------------------------------------------------------------------
// GEMM1: Qh[r,e] = sum_d G[r,d]*Wq[e,d] + bq[e]   (r = b*3+q, G gathered from globals)
// 32x32 tile, 256 threads, 2x2 microtile, fp64 accumulate.
// ---------------------------------------------------------------------------
__global__ __launch_bounds__(256) void gemm_q(
    const float* __restrict__ g0, const float* __restrict__ g1,
    const float* __restrict__ g2, const float* __restrict__ Wq,
    const float* __restrict__ bq, double* __restrict__ Qh)
{
    __shared__ float As[32][33];
    __shared__ float Ws[32][33];
    const int t  = threadIdx.x;
    const int tx = t & 15, ty = t >> 4;
    const int i0 = blockIdx.y * 32, j0 = blockIdx.x * 32;
    double a00 = 0, a01 = 0, a10 = 0, a11 = 0;
    for (int kk = 0; kk < DD; kk += 32) {
        for (int s = 0; s < 4; ++s) {
            int idx = t + s * 256;
            int r = idx >> 5, c = idx & 31;
            int row = i0 + r;
            int b = row / 3, q = row - b * 3;
            const float* gp = (q == 0) ? g0 : (q == 1) ? g1 : g2;
            As[r][c] = gp[b * DD + kk + c];
            Ws[r][c] = Wq[(j0 + r) * DD + kk + c];
        }
        __syncthreads();
        for (int k = 0; k < 32; ++k) {
            double x0 = (double)As[ty][k],      x1 = (double)As[ty + 16][k];
            double y0 = (double)Ws[tx][k],      y1 = (double)Ws[tx + 16][k];
            a00 += x0 * y0; a01 += x0 * y1; a10 += x1 * y0; a11 += x1 * y1;
        }
        __syncthreads();
    }
    Qh[(i0 + ty) * DD + j0 + tx]           = a00 + (double)bq[j0 + tx];
    Qh[(i0 + ty) * DD + j0 + tx + 16]      = a01 + (double)bq[j0 + tx + 16];
    Qh[(i0 + ty + 16) * DD + j0 + tx]      = a10 + (double)bq[j0 + tx];
    Qh[(i0 + ty + 16) * DD + j0 + tx + 16] = a11 + (double)bq[j0 + tx + 16];
}

// ---------------------------------------------------------------------------
// GEMM2: Td[r,d] = sum_e Qh[r,e]*Wk[e,d]     (no transpose on Wk)
// ---------------------------------------------------------------------------
__global__ __launch_bounds__(256) void gemm_t(
    const double* __restrict__ Qh, const float* __restrict__ Wk,
    double* __restrict__ Td)
{
    __shared__ double As[32][33];
    __shared__ float  Ws[32][33];
    const int t  = threadIdx.x;
    const int tx = t & 15, ty = t >> 4;
    const int i0 = blockIdx.y * 32, j0 = blockIdx.x * 32;
    double a00 = 0, a01 = 0, a10 = 0, a11 = 0;
    for (int kk = 0; kk < DD; kk += 32) {
        for (int s = 0; s < 4; ++s) {
            int idx = t + s * 256;
            int r = idx >> 5, c = idx & 31;
            As[r][c] = Qh[(i0 + r) * DD + kk + c];
            Ws[r][c] = Wk[(kk + r) * DD + j0 + c];
        }
        __syncthreads();
        for (int k = 0; k < 32; ++k) {
            double x0 = As[ty][k],            x1 = As[ty + 16][k];
            double y0 = (double)Ws[k][tx],    y1 = (double)Ws[k][tx + 16];
            a00 += x0 * y0; a01 += x0 * y1; a10 += x1 * y0; a11 += x1 * y1;
        }
        __syncthreads();
    }
    Td[(i0 + ty) * DD + j0 + tx]           = a00;
    Td[(i0 + ty) * DD + j0 + tx + 16]      = a01;
    Td[(i0 + ty + 16) * DD + j0 + tx]      = a10;
    Td[(i0 + ty + 16) * DD + j0 + tx + 16] = a11;
}

// ---------------------------------------------------------------------------
// Scoring: one block per (b, m). Reads patches[b,m] ONCE, computes
//   intra logit  = dot(global_m[b], patch)            -> Lintra[b*3+m, n]
//   inter logits = dot(T[b,qa], patch), dot(T[b,qb], patch)
//                  -> Linter[b*3+q', slot*196 + n]  for the two queries q' != m
// wave-per-row, float4 global loads, fp64 accumulate, shfl reduction.
// ---------------------------------------------------------------------------
__global__ __launch_bounds__(256) void score_kernel(
    const float* __restrict__ p0, const float* __restrict__ p1,
    const float* __restrict__ p2, const float* __restrict__ g0,
    const float* __restrict__ g1, const float* __restrict__ g2,
    const double* __restrict__ Td, double* __restrict__ Lintra,
    double* __restrict__ Linter)
{
    const int bm = blockIdx.x;            // b*3 + m
    const int b = bm / 3, m = bm - b * 3;
    __shared__ double gd[DD], Ta[DD], Tb[DD];

    const float* gp = (m == 0) ? g0 : (m == 1) ? g1 : g2;
    const float* pp = (m == 0) ? p0 : (m == 1) ? p1 : p2;
    // queries for which modality m is a candidate, ascending
    const int qa = (m == 0) ? 1 : 0;
    const int qb = (m == 2) ? 1 : 2;
    const int slota = m - (m > qa ? 1 : 0);   // position of m in q's candidate list
    const int slotb = m - (m > qb ? 1 : 0);

    for (int d = threadIdx.x; d < DD; d += 256) {
        gd[d] = (double)gp[b * DD + d];
        Ta[d] = Td[(b * 3 + qa) * DD + d];
        Tb[d] = Td[(b * 3 + qb) * DD + d];
    }
    __syncthreads();

    const int wave = threadIdx.x >> 6, lane = threadIdx.x & 63;
    for (int n = wave; n < NN; n += 4) {
        const float4* row = (const float4*)(pp + (size_t)(b * NN + n) * DD);
        double s0 = 0, s1 = 0, s2 = 0;
        for (int c = lane; c < DD / 4; c += 64) {
            float4 v = row[c];
            int d = c * 4;
            s0 += gd[d] * (double)v.x + gd[d + 1] * (double)v.y
                + gd[d + 2] * (double)v.z + gd[d + 3] * (double)v.w;
            s1 += Ta[d] * (double)v.x + Ta[d + 1] * (double)v.y
                + Ta[d + 2] * (double)v.z + Ta[d + 3] * (double)v.w;
            s2 += Tb[d] * (double)v.x + Tb[d + 1] * (double)v.y
                + Tb[d + 2] * (double)v.z + Tb[d + 3] * (double)v.w;
        }
        for (int off = 32; off > 0; off >>= 1) {
            s0 += __shfl_down(s0, off);
            s1 += __shfl_down(s1, off);
            s2 += __shfl_down(s2, off);
        }
        if (lane == 0) {
            Lintra[bm * NN + n]                          = s0;
            Linter[(b * 3 + qa) * CAND + slota * NN + n] = s1;
            Linter[(b * 3 + qb) * CAND + slotb * NN + n] = s2;
        }
    }
}

// ---------------------------------------------------------------------------
// Intra rank: block per (b,m); token t selected iff rank<112 (ties by index).
// ---------------------------------------------------------------------------
__global__ __launch_bounds__(256) void rank_intra(
    const double* __restrict__ Lintra, unsigned char* __restrict__ mask)
{
    const int bm = blockIdx.x;
    const int b = bm / 3, m = bm - b * 3;
    __shared__ double L[NN];
    for (int i = threadIdx.x; i < NN; i += 256) L[i] = Lintra[bm * NN + i];
    __syncthreads();
    const int t = threadIdx.x;
    if (t < NN) {
        double v = L[t];
        int rank = 0;
        for (int j = 0; j < NN; ++j) {
            double u = L[j];
            rank += (u > v) || (u == v && j < t);
        }
        if (rank < KK1) mask[m * (BB * NN) + b * NN + t] = 1;
    }
}

// ---------------------------------------------------------------------------
// Inter rank: block per (b,q); candidate c of 392 selected iff rank<224,
// then routed to (modality, token) per reference candidate ordering.
// ---------------------------------------------------------------------------
__global__ __launch_bounds__(256) void rank_inter(
    const double* __restrict__ Linter, unsigned char* __restrict__ mask)
{
    const int bq = blockIdx.x;
    const int b = bq / 3, q = bq - b * 3;
    __shared__ double L[CAND];
    for (int i = threadIdx.x; i < CAND; i += 256) L[i] = Linter[bq * CAND + i];
    __syncthreads();
    const int ma = (q == 0) ? 1 : 0;   // first candidate modality
    const int mb = (q == 2) ? 1 : 2;   // second candidate modality
    for (int t = threadIdx.x; t < CAND; t += 256) {
        double v = L[t];
        int rank = 0;
        for (int j = 0; j < CAND; ++j) {
            double u = L[j];
            rank += (u > v) || (u == v && j < t);
        }
        if (rank < KK2) {
            int mm  = (t < NN) ? ma : mb;
            int tok = (t < NN) ? t : t - NN;
            mask[mm * (BB * NN) + b * NN + tok] = 1;
        }
    }
}

// ---------------------------------------------------------------------------
// Final: out[row,:] = mask[row] ? patches[row,:] : 0.   row = m*50176+b*196+n
// 192 threads/block (3 waves), float4 per thread. Branch is block-uniform.
// ---------------------------------------------------------------------------
__global__ __launch_bounds__(192) void apply_mask(
    const float* __restrict__ p0, const float* __restrict__ p1,
    const float* __restrict__ p2, const unsigned char* __restrict__ mask,
    float* __restrict__ out)
{
    const int row  = blockIdx.x;
    const int m    = row / (BB * NN);
    const int lrow = row - m * (BB * NN);
    const float* pp = (m == 0) ? p0 : (m == 1) ? p1 : p2;
    const float4* src = (const float4*)(pp + (size_t)lrow * DD);
    float4*       dst = (float4*)(out + (size_t)row * DD);
    if (mask[row]) {
        dst[threadIdx.x] = src[threadIdx.x];
    } else {
        float4 z; z.x = 0.f; z.y = 0.f; z.z = 0.f; z.w = 0.f;
        dst[threadIdx.x] = z;
    }
}

extern "C" void kernel_launch(void* const* d_in, const int* in_sizes, int n_in,
                              void* d_out, int out_size, void* d_ws, size_t ws_size,
                              hipStream_t stream) {
    const float* p0 = (const float*)d_in[0];   // rgb_patches
    const float* p1 = (const float*)d_in[1];   // nir_patches
    const float* p2 = (const float*)d_in[2];   // tir_patches
    const float* g0 = (const float*)d_in[3];   // rgb_global
    const float* g1 = (const float*)d_in[4];   // nir_global
    const float* g2 = (const float*)d_in[5];   // tir_global
    const float* Wq = (const float*)d_in[6];
    const float* bq = (const float*)d_in[7];
    const float* Wk = (const float*)d_in[8];
    // d_in[9] = bk: adds a per-(b,q)-row constant to all candidates -> cannot
    // affect top-k ordering; intentionally unused.

    char* ws = (char*)d_ws;
    double*        Qh     = (double*)(ws);
    double*        Td     = (double*)(ws + 4718592);
    double*        Lintra = (double*)(ws + 9437184);
    double*        Linter = (double*)(ws + 10641408);
    unsigned char* mask   = (unsigned char*)(ws + 13049856);

    hipMemsetAsync(mask, 0, 3 * BB * NN, stream);

    dim3 ggrid(DD / 32, RTOT / 32);   // (24, 24)
    gemm_q<<<ggrid, 256, 0, stream>>>(g0, g1, g2, Wq, bq, Qh);
    gemm_t<<<ggrid, 256, 0, stream>>>(Qh, Wk, Td);
    score_kernel<<<RTOT, 256, 0, stream>>>(p0, p1, p2, g0, g1, g2, Td, Lintra, Linter);
    rank_intra<<<RTOT, 256, 0, stream>>>(Lintra, mask);
    rank_inter<<<RTOT, 256, 0, stream>>>(Linter, mask);
    apply_mask<<<3 * BB * NN, 192, 0, stream>>>(p0, p1, p2, mask, (float*)d_out);
}